// Round 3
// baseline (8419.218 us; speedup 1.0000x reference)
//
#include <hip/hip_runtime.h>
#include <hip/hip_bf16.h>

// Bidirectional LSTM, B=32 T=512 D=H=512. ALL I/O IS FLOAT32 (per reference
// dtypes; mask int32). Internally bf16 MFMA with f32 accumulation.
//
// Single persistent kernel: grid = (32 slices, 2 dirs), 256 thr/wg.
// Slice s owns h-cols [16s,16s+16) => 64 gate rows; wave w = gate (i,f,g,o).
// W_ih and W_hh slices converted f32->bf16 once into VGPRs (16 bf16x8 each).
// Per step: stage x-rows (f32->bf16 via regs) + h (bf16, global_load_lds w16)
// into XOR-swizzled LDS, 64 MFMAs (x@Wih^T + h@Whh^T + bias), cell update,
// h -> global bf16 double buffer, f32 h -> out, one device-scope atomic
// barrier per direction per step. Workspace use ~133 KB.

typedef __bf16 bf16;
typedef __attribute__((ext_vector_type(8))) __bf16 bf16x8;
typedef __attribute__((ext_vector_type(4))) float f32x4;

#define AS1 __attribute__((address_space(1)))
#define AS3 __attribute__((address_space(3)))

__device__ __forceinline__ void gload_lds16(const void* g, void* l) {
  __builtin_amdgcn_global_load_lds((AS1 void*)g, (AS3 void*)l, 16, 0, 0);
}

__device__ __forceinline__ float sigmoidf_(float x) {
  return 1.f / (1.f + __expf(-x));
}
__device__ __forceinline__ float tanhf_(float x) {
  float e = __expf(-2.f * fabsf(x));
  return copysignf((1.f - e) / (1.f + e), x);
}

// 8 consecutive f32 -> bf16x8 (RNE via __bf16 cast)
__device__ __forceinline__ bf16x8 cvt8(const float* p) {
  float4 a = *(const float4*)p;
  float4 b = *(const float4*)(p + 4);
  bf16x8 v;
  v[0] = (bf16)a.x; v[1] = (bf16)a.y; v[2] = (bf16)a.z; v[3] = (bf16)a.w;
  v[4] = (bf16)b.x; v[5] = (bf16)b.y; v[6] = (bf16)b.z; v[7] = (bf16)b.w;
  return v;
}

// ---------------- lengths: L[b] = sum(mask[b,:]) ----------------
__global__ void lengths_kernel(const int* __restrict__ mask, int* __restrict__ lengths) {
  __shared__ int part[32][8];
  int t = threadIdx.x;            // 256 threads
  int b = t >> 3, sub = t & 7;
  int s = 0;
#pragma unroll 8
  for (int k = 0; k < 64; ++k) s += mask[b * 512 + sub + 8 * k];
  part[b][sub] = s;
  __syncthreads();
  if (sub == 0) {
    int tot = 0;
#pragma unroll
    for (int k = 0; k < 8; ++k) tot += part[b][k];
    lengths[b] = tot;
  }
}

// ---------------- fused persistent LSTM ----------------
__global__ __launch_bounds__(256, 1) void lstm_fused(
    const float* __restrict__ x,                                  // [32][512][512] f32
    const float* __restrict__ Wih_f, const float* __restrict__ bih_f,
    const float* __restrict__ Whh_f,
    const float* __restrict__ Wih_b, const float* __restrict__ bih_b,
    const float* __restrict__ Whh_b,
    const int* __restrict__ lengths,
    bf16* __restrict__ hbuf,            // [2 dir][2 parity][32][512] bf16
    unsigned int* __restrict__ barcnt,  // [2] counters, 256B apart
    float* __restrict__ out) {          // [32][512][1024] f32
  const int s = blockIdx.x;             // h-col slice
  const int dir = blockIdx.y;
  const float* Wih = dir ? Wih_b : Wih_f;
  const float* Whh = dir ? Whh_b : Whh_f;
  const float* bih = dir ? bih_b : bih_f;
  unsigned int* cnt = barcnt + dir * 64;

  const int tid = threadIdx.x;
  const int lane = tid & 63, wave = tid >> 6;
  const int l15 = lane & 15, quad = lane >> 4;

  __shared__ __align__(16) bf16 xA[32 * 512];   // 32 KB, XOR-swizzled chunks
  __shared__ __align__(16) bf16 hA[32 * 512];   // 32 KB
  __shared__ float vbuf[4][32][17];             // gate pre-activations (+1 pad)
  __shared__ int lenL[32];

  // Weight slices f32 -> bf16 registers. B-frag for MFMA #k: lane holds
  // W[n = grow][k*32 + quad*8 + j], j=0..7  (B layout: k=quad*8+j, n=l15).
  bf16x8 wih[16], whh[16];
  {
    int grow = wave * 512 + s * 16 + l15;       // gate row
#pragma unroll
    for (int k = 0; k < 16; ++k) {
      wih[k] = cvt8(Wih + (size_t)grow * 512 + k * 32 + quad * 8);
      whh[k] = cvt8(Whh + (size_t)grow * 512 + k * 32 + quad * 8);
    }
  }
  const float bv = bih[wave * 512 + s * 16 + l15];

  if (tid < 32) lenL[tid] = lengths[tid];
  __syncthreads();

  float creg[2] = {0.f, 0.f};                   // cell state, 2 (b,j) pairs/thread
  bf16* hb = hbuf + dir * (2 * 32 * 512);

  for (int step = 0; step < 512; ++step) {
    const int par = step & 1;
    const bf16* hprev = hb + par * (32 * 512);
    bf16* hnext = hb + (par ^ 1) * (32 * 512);

    // h[32][512] bf16 -> LDS via async global_load_lds (wave-uniform base + lane*16 OK:
    // c = i*256 + wave*64 + lane). Phys chunk c (m=c>>6, kbp=c&63) holds logical kb=kbp^(m&7).
#pragma unroll
    for (int i = 0; i < 8; ++i) {
      int c = i * 256 + tid;
      int m = c >> 6, kbp = c & 63;
      int kb = kbp ^ (m & 7);
      gload_lds16(hprev + m * 512 + kb * 8, hA + c * 8);
    }
    // x rows f32 -> cvt -> bf16 LDS (same swizzled layout), 8 chunks/thread
#pragma unroll
    for (int i = 0; i < 8; ++i) {
      int c = i * 256 + tid;
      int m = c >> 6, kbp = c & 63;
      int kb = kbp ^ (m & 7);
      int tr = (dir == 0) ? step : ((511 - step + lenL[m]) & 511);
      *(bf16x8*)(xA + c * 8) = cvt8(x + (size_t)(m * 512 + tr) * 512 + kb * 8);
    }
    __syncthreads();   // drains vmcnt (async h) + lgkmcnt (ds_write x)

    // v[32 x 16] = x@Wih^T + h@Whh^T + bias ; 2 batch-tiles x 16 ksteps x 2 inputs
    f32x4 acc0 = {bv, bv, bv, bv};
    f32x4 acc1 = {bv, bv, bv, bv};
#pragma unroll
    for (int k = 0; k < 16; ++k) {
      int kb = k * 4 + quad;
      int sw = (kb ^ (l15 & 7)) * 8;            // (16+l15)&7 == l15&7
      bf16x8 ax0 = *(const bf16x8*)(xA + l15 * 512 + sw);
      bf16x8 ah0 = *(const bf16x8*)(hA + l15 * 512 + sw);
      bf16x8 ax1 = *(const bf16x8*)(xA + (16 + l15) * 512 + sw);
      bf16x8 ah1 = *(const bf16x8*)(hA + (16 + l15) * 512 + sw);
      acc0 = __builtin_amdgcn_mfma_f32_16x16x32_bf16(ax0, wih[k], acc0, 0, 0, 0);
      acc0 = __builtin_amdgcn_mfma_f32_16x16x32_bf16(ah0, whh[k], acc0, 0, 0, 0);
      acc1 = __builtin_amdgcn_mfma_f32_16x16x32_bf16(ax1, wih[k], acc1, 0, 0, 0);
      acc1 = __builtin_amdgcn_mfma_f32_16x16x32_bf16(ah1, whh[k], acc1, 0, 0, 0);
    }
    // C/D: col = lane&15 (gate col n), row = quad*4+reg (batch)
#pragma unroll
    for (int r = 0; r < 4; ++r) {
      vbuf[wave][quad * 4 + r][l15] = acc0[r];
      vbuf[wave][16 + quad * 4 + r][l15] = acc1[r];
    }
    __syncthreads();

    // Cell update; each thread owns 2 (b, j) pairs with persistent c in registers.
#pragma unroll
    for (int rep = 0; rep < 2; ++rep) {
      int p = tid + rep * 256;
      int b = p >> 4, j = p & 15;
      int tr = (dir == 0) ? step : ((511 - step + lenL[b]) & 511);
      float iv = vbuf[0][b][j];
      float fv = vbuf[1][b][j];
      float gv = vbuf[2][b][j];
      float ov = vbuf[3][b][j];
      float c = sigmoidf_(fv) * creg[rep] + sigmoidf_(iv) * tanhf_(gv);
      creg[rep] = c;
      float h = tanhf_(c) * sigmoidf_(ov);
      hnext[b * 512 + s * 16 + j] = (bf16)h;
      out[(size_t)(b * 512 + tr) * 1024 + dir * 512 + s * 16 + j] = h;
    }

    if (step < 511) {
      // Inter-workgroup barrier (per direction, 32 wgs, monotone counter).
      __threadfence();      // release: h stores visible device-wide
      __syncthreads();
      if (tid == 0) {
        __hip_atomic_fetch_add(cnt, 1u, __ATOMIC_RELEASE, __HIP_MEMORY_SCOPE_AGENT);
        unsigned int target = 32u * (unsigned)(step + 1);
        while (__hip_atomic_load(cnt, __ATOMIC_ACQUIRE, __HIP_MEMORY_SCOPE_AGENT) < target)
          __builtin_amdgcn_s_sleep(2);
      }
      __syncthreads();
      __threadfence();      // acquire: no stale h from caches
    }
  }
}

extern "C" void kernel_launch(void* const* d_in, const int* in_sizes, int n_in,
                              void* d_out, int out_size, void* d_ws, size_t ws_size,
                              hipStream_t stream) {
  (void)in_sizes; (void)n_in; (void)out_size; (void)ws_size;
  const float* x    = (const float*)d_in[0];
  const int*   mask = (const int*)  d_in[1];
  const float* Wihf = (const float*)d_in[2];
  const float* bihf = (const float*)d_in[3];
  const float* Whhf = (const float*)d_in[4];
  const float* Wihb = (const float*)d_in[5];
  const float* bihb = (const float*)d_in[6];
  const float* Whhb = (const float*)d_in[7];
  float* out = (float*)d_out;

  char* ws = (char*)d_ws;
  unsigned int* barcnt = (unsigned int*)ws;   // 2 counters @ ws+0, ws+256
  int* lengths = (int*)(ws + 512);            // 128 B
  bf16* hbuf = (bf16*)(ws + 1024);            // 2*2*32*512*2 = 131072 B
  const size_t head = 1024 + (size_t)2 * 2 * 32 * 512 * sizeof(bf16);

  hipMemsetAsync(d_ws, 0, head, stream);      // re-arm barriers + h0 = c0 = 0 every call
  lengths_kernel<<<1, 256, 0, stream>>>(mask, lengths);
  lstm_fused<<<dim3(32, 2), 256, 0, stream>>>(
      x, Wihf, bihf, Whhf, Wihb, bihb, Whhb, lengths, hbuf, barcnt, out);
}

// Round 4
// 2853.439 us; speedup vs baseline: 2.9506x; 2.9506x over previous
//
#include <hip/hip_runtime.h>
#include <hip/hip_bf16.h>

// Bidirectional LSTM, B=32 T=512 D=H=512. f32 I/O, bf16 MFMA internally.
//
// Persistent kernel, grid=(32 slices, 2 dirs), 256 thr/wg, 1 step = 1 device
// barrier per direction. KEY CHANGE vs R3: no agent-scope fences / acquire
// atomics anywhere (those emitted buffer_wbl2/buffer_inv = full L2
// writeback+invalidate per poll -> 16 us/step). Instead:
//   - h exchange via RELAXED agent-scope atomics (device-coherent, bypass
//     stale L1/L2 by construction; no cache maintenance instructions).
//   - barrier counter via RELAXED fetch_add + RELAXED poll.
//   - store->signal ordering from __syncthreads() (per-wave vmcnt(0) drain
//     before s_barrier); signal->load ordering needs nothing because h loads
//     are coherent.
//   - x rows for step+1 prefetched into registers behind the barrier wait.

typedef __bf16 bf16;
typedef __attribute__((ext_vector_type(8))) __bf16 bf16x8;
typedef __attribute__((ext_vector_type(4))) float f32x4;

__device__ __forceinline__ float sigmoidf_(float x) {
  return 1.f / (1.f + __expf(-x));
}
__device__ __forceinline__ float tanhf_(float x) {
  float e = __expf(-2.f * fabsf(x));
  return copysignf((1.f - e) / (1.f + e), x);
}

__device__ __forceinline__ unsigned ald(const unsigned* p) {
  return __hip_atomic_load(p, __ATOMIC_RELAXED, __HIP_MEMORY_SCOPE_AGENT);
}
__device__ __forceinline__ void ast(unsigned* p, unsigned v) {
  __hip_atomic_store(p, v, __ATOMIC_RELAXED, __HIP_MEMORY_SCOPE_AGENT);
}

// 8 consecutive f32 -> bf16x8 (RNE via __bf16 cast)
__device__ __forceinline__ bf16x8 cvt8v(float4 a, float4 b) {
  bf16x8 v;
  v[0] = (bf16)a.x; v[1] = (bf16)a.y; v[2] = (bf16)a.z; v[3] = (bf16)a.w;
  v[4] = (bf16)b.x; v[5] = (bf16)b.y; v[6] = (bf16)b.z; v[7] = (bf16)b.w;
  return v;
}

// ---------------- lengths: L[b] = sum(mask[b,:]) ----------------
__global__ void lengths_kernel(const int* __restrict__ mask, int* __restrict__ lengths) {
  __shared__ int part[32][8];
  int t = threadIdx.x;            // 256 threads
  int b = t >> 3, sub = t & 7;
  int s = 0;
#pragma unroll 8
  for (int k = 0; k < 64; ++k) s += mask[b * 512 + sub + 8 * k];
  part[b][sub] = s;
  __syncthreads();
  if (sub == 0) {
    int tot = 0;
#pragma unroll
    for (int k = 0; k < 8; ++k) tot += part[b][k];
    lengths[b] = tot;
  }
}

// ---------------- fused persistent LSTM ----------------
__global__ __launch_bounds__(256, 1) void lstm_fused(
    const float* __restrict__ x,                                  // [32][512][512] f32
    const float* __restrict__ Wih_f, const float* __restrict__ bih_f,
    const float* __restrict__ Whh_f,
    const float* __restrict__ Wih_b, const float* __restrict__ bih_b,
    const float* __restrict__ Whh_b,
    const int* __restrict__ lengths,
    unsigned* __restrict__ hbuf,        // [2 dir][2 parity][32][256] dwords (2 bf16 each)
    unsigned* __restrict__ barcnt,      // [2] counters, 256B apart
    float* __restrict__ out) {          // [32][512][1024] f32
  const int s = blockIdx.x;             // h-col slice: cols [16s, 16s+16)
  const int dir = blockIdx.y;
  const float* Wih = dir ? Wih_b : Wih_f;
  const float* Whh = dir ? Whh_b : Whh_f;
  const float* bih = dir ? bih_b : bih_f;
  unsigned* cnt = barcnt + dir * 64;

  const int tid = threadIdx.x;
  const int lane = tid & 63, wave = tid >> 6;
  const int l15 = lane & 15, quad = lane >> 4;

  __shared__ __align__(16) bf16 xA[32 * 512];   // 32 KB, XOR-swizzled chunks
  __shared__ __align__(16) bf16 hA[32 * 512];   // 32 KB
  __shared__ float vbuf[4][32][17];             // gate pre-activations (+1 pad)
  __shared__ int lenL[32];

  // Weight slices f32 -> bf16 registers. B-frag for MFMA #k: lane holds
  // W[n = grow][k*32 + quad*8 + j], j=0..7  (B layout: k=quad*8+j, n=l15).
  bf16x8 wih[16], whh[16];
  {
    int grow = wave * 512 + s * 16 + l15;       // gate row
#pragma unroll
    for (int k = 0; k < 16; ++k) {
      const float* pw = Wih + (size_t)grow * 512 + k * 32 + quad * 8;
      const float* ph = Whh + (size_t)grow * 512 + k * 32 + quad * 8;
      wih[k] = cvt8v(*(const float4*)pw, *(const float4*)(pw + 4));
      whh[k] = cvt8v(*(const float4*)ph, *(const float4*)(ph + 4));
    }
  }
  const float bv = bih[wave * 512 + s * 16 + l15];

  if (tid < 32) lenL[tid] = lengths[tid];
  __syncthreads();

  // cell mapping: thread owns batch b = tid>>3, cols j2 = (tid&7)*2 and j2+1
  const int cb = tid >> 3, cj = (tid & 7) * 2;
  float creg0 = 0.f, creg1 = 0.f;
  unsigned* hb = hbuf + dir * (2 * 32 * 256);

  // x prefetch registers (8 chunks x 32 B)
  float4 xp[8][2];
#pragma unroll
  for (int i = 0; i < 8; ++i) {
    int c = i * 256 + tid;
    int m = c >> 6, kbp = c & 63;
    int kb = kbp ^ (m & 7);
    int tr = (dir == 0) ? 0 : ((511 + lenL[m]) & 511);
    const float4* p = (const float4*)(x + ((size_t)m * 512 + tr) * 512 + kb * 8);
    xp[i][0] = p[0];
    xp[i][1] = p[1];
  }

  for (int step = 0; step < 512; ++step) {
    const int par = step & 1;
    const unsigned* hprev = hb + par * (32 * 256);
    unsigned* hnext = hb + (par ^ 1) * (32 * 256);

    // h[32][512] -> LDS via coherent dword loads (4/chunk) + ds_write_b128.
    // Phys chunk c (m=c>>6, kbp=c&63) holds logical k-chunk kb=kbp^(m&7).
#pragma unroll
    for (int i = 0; i < 8; ++i) {
      int c = i * 256 + tid;
      int m = c >> 6, kbp = c & 63;
      int kb = kbp ^ (m & 7);
      const unsigned* hp = hprev + m * 256 + kb * 4;
      uint4 d;
      d.x = ald(hp); d.y = ald(hp + 1); d.z = ald(hp + 2); d.w = ald(hp + 3);
      *(uint4*)(hA + c * 8) = d;
    }
    // x chunks: cvt prefetched f32 regs -> bf16 LDS (same swizzled layout)
#pragma unroll
    for (int i = 0; i < 8; ++i) {
      int c = i * 256 + tid;
      *(bf16x8*)(xA + c * 8) = cvt8v(xp[i][0], xp[i][1]);
    }
    __syncthreads();

    // v[32 x 16] = x@Wih^T + h@Whh^T + bias ; 2 batch-tiles x 16 ksteps x 2 inputs
    f32x4 acc0 = {bv, bv, bv, bv};
    f32x4 acc1 = {bv, bv, bv, bv};
#pragma unroll
    for (int k = 0; k < 16; ++k) {
      int kb = k * 4 + quad;
      int sw = (kb ^ (l15 & 7)) * 8;            // (16+l15)&7 == l15&7
      bf16x8 ax0 = *(const bf16x8*)(xA + l15 * 512 + sw);
      bf16x8 ah0 = *(const bf16x8*)(hA + l15 * 512 + sw);
      bf16x8 ax1 = *(const bf16x8*)(xA + (16 + l15) * 512 + sw);
      bf16x8 ah1 = *(const bf16x8*)(hA + (16 + l15) * 512 + sw);
      acc0 = __builtin_amdgcn_mfma_f32_16x16x32_bf16(ax0, wih[k], acc0, 0, 0, 0);
      acc0 = __builtin_amdgcn_mfma_f32_16x16x32_bf16(ah0, whh[k], acc0, 0, 0, 0);
      acc1 = __builtin_amdgcn_mfma_f32_16x16x32_bf16(ax1, wih[k], acc1, 0, 0, 0);
      acc1 = __builtin_amdgcn_mfma_f32_16x16x32_bf16(ah1, whh[k], acc1, 0, 0, 0);
    }
    // C/D: col = lane&15 (gate col), row = quad*4+reg (batch)
#pragma unroll
    for (int r = 0; r < 4; ++r) {
      vbuf[wave][quad * 4 + r][l15] = acc0[r];
      vbuf[wave][16 + quad * 4 + r][l15] = acc1[r];
    }
    __syncthreads();

    // Cell update: thread owns (cb, cj) and (cb, cj+1); c-state in registers.
    float i0 = vbuf[0][cb][cj],     f0 = vbuf[1][cb][cj];
    float g0 = vbuf[2][cb][cj],     o0 = vbuf[3][cb][cj];
    float i1 = vbuf[0][cb][cj + 1], f1 = vbuf[1][cb][cj + 1];
    float g1 = vbuf[2][cb][cj + 1], o1 = vbuf[3][cb][cj + 1];
    float c0 = sigmoidf_(f0) * creg0 + sigmoidf_(i0) * tanhf_(g0);
    float c1 = sigmoidf_(f1) * creg1 + sigmoidf_(i1) * tanhf_(g1);
    creg0 = c0; creg1 = c1;
    float h0 = tanhf_(c0) * sigmoidf_(o0);
    float h1 = tanhf_(c1) * sigmoidf_(o1);
    // packed coherent h store: 1 dword = 2 bf16
    unsigned ulo = (unsigned)__builtin_bit_cast(unsigned short, (bf16)h0);
    unsigned uhi = (unsigned)__builtin_bit_cast(unsigned short, (bf16)h1);
    ast(hnext + cb * 256 + s * 8 + (tid & 7), ulo | (uhi << 16));

    __syncthreads();   // all threads stored h; per-wave vmcnt(0) drained before s_barrier
    if (tid == 0)
      __hip_atomic_fetch_add(cnt, 1u, __ATOMIC_RELAXED, __HIP_MEMORY_SCOPE_AGENT);

    // work that hides the barrier wait: out store + next-step x prefetch
    {
      int tr = (dir == 0) ? step : ((511 - step + lenL[cb]) & 511);
      *(float2*)(out + (size_t)(cb * 512 + tr) * 1024 + dir * 512 + s * 16 + cj) =
          make_float2(h0, h1);
    }
    if (step < 511) {
#pragma unroll
      for (int i = 0; i < 8; ++i) {
        int c = i * 256 + tid;
        int m = c >> 6, kbp = c & 63;
        int kb = kbp ^ (m & 7);
        int tr = (dir == 0) ? (step + 1) : ((510 - step + lenL[m]) & 511);
        const float4* p = (const float4*)(x + ((size_t)m * 512 + tr) * 512 + kb * 8);
        xp[i][0] = p[0];
        xp[i][1] = p[1];
      }
      if (tid == 0) {
        unsigned target = 32u * (unsigned)(step + 1);
        while (ald(cnt) < target) __builtin_amdgcn_s_sleep(1);
      }
      __syncthreads();
    }
  }
}

extern "C" void kernel_launch(void* const* d_in, const int* in_sizes, int n_in,
                              void* d_out, int out_size, void* d_ws, size_t ws_size,
                              hipStream_t stream) {
  (void)in_sizes; (void)n_in; (void)out_size; (void)ws_size;
  const float* x    = (const float*)d_in[0];
  const int*   mask = (const int*)  d_in[1];
  const float* Wihf = (const float*)d_in[2];
  const float* bihf = (const float*)d_in[3];
  const float* Whhf = (const float*)d_in[4];
  const float* Wihb = (const float*)d_in[5];
  const float* bihb = (const float*)d_in[6];
  const float* Whhb = (const float*)d_in[7];
  float* out = (float*)d_out;

  char* ws = (char*)d_ws;
  unsigned* barcnt = (unsigned*)ws;           // 2 counters @ ws+0, ws+256
  int* lengths = (int*)(ws + 512);            // 128 B
  unsigned* hbuf = (unsigned*)(ws + 1024);    // 2*2*32*256*4 = 131072 B
  const size_t head = 1024 + (size_t)2 * 2 * 32 * 256 * sizeof(unsigned);

  hipMemsetAsync(d_ws, 0, head, stream);      // re-arm barriers + h0 = c0 = 0 every call
  lengths_kernel<<<1, 256, 0, stream>>>(mask, lengths);
  lstm_fused<<<dim3(32, 2), 256, 0, stream>>>(
      x, Wihf, bihf, Whhf, Wihb, bihb, Whhb, lengths, hbuf, barcnt, out);
}